// Round 4
// baseline (399.460 us; speedup 1.0000x reference)
//
#include <hip/hip_runtime.h>
#include <math.h>

typedef __bf16 bf16x8 __attribute__((ext_vector_type(8)));
typedef __bf16 bf16x4 __attribute__((ext_vector_type(4)));
typedef float f32x4 __attribute__((ext_vector_type(4)));

#define HD 1024
#define SEQ 2048
#define NB 4
#define WEL (HD * HD)   // elements per weight matrix

// Load 8 contiguous elements as bf16x8, converting f32 -> bf16 if needed.
__device__ inline bf16x8 load8cvt(const __bf16* p) { return *(const bf16x8*)p; }
__device__ inline bf16x8 load8cvt(const float* p) {
    f32x4 a = *(const f32x4*)p;
    f32x4 b = *(const f32x4*)(p + 4);
    bf16x8 r;
#pragma unroll
    for (int i = 0; i < 4; ++i) { r[i] = (__bf16)a[i]; r[i + 4] = (__bf16)b[i]; }
    return r;
}

// Load 4 contiguous elements as f32x4 (from f32 or bf16 source).
__device__ inline f32x4 load4f(const float* p) { return *(const f32x4*)p; }
__device__ inline f32x4 load4f(const __bf16* p) {
    bf16x4 v = *(const bf16x4*)p;
    f32x4 r;
#pragma unroll
    for (int i = 0; i < 4; ++i) r[i] = (float)v[i];
    return r;
}

// Async global->LDS, 16 bytes per lane (global_load_lds_dwordx4).
__device__ inline void gld_lds16(const void* g, void* l) {
    __builtin_amdgcn_global_load_lds(
        (const __attribute__((address_space(1))) unsigned int*)g,
        (__attribute__((address_space(3))) unsigned int*)l, 16, 0, 0);
}

#define VMC(N) asm volatile("s_waitcnt vmcnt(" #N ")" ::: "memory")

// ===========================================================================
// Legacy 128x128 BK=64 structure (scores / ctx / fallback kernels)
// ===========================================================================
template <typename T>
__device__ inline void stage_tile(const T* __restrict__ G, int ld, __bf16* s, int tid)
{
    const int r  = tid >> 3;                          // 0..31
    const int co = ((tid & 7) ^ (r & 7)) * 8;         // swizzled source column
    if constexpr (sizeof(T) == 2) {
        __bf16* dst = s + (tid >> 6) * 512;           // wave-uniform base
#pragma unroll
        for (int c = 0; c < 4; ++c)
            gld_lds16(G + (long)(c * 32 + r) * ld + co, dst + c * 2048);
    } else {
#pragma unroll
        for (int c = 0; c < 4; ++c)
            *(bf16x8*)(s + c * 2048 + tid * 8) = load8cvt(G + (long)(c * 32 + r) * ld + co);
    }
}

__device__ inline bf16x8 frag_read(const __bf16* s, int row, int c)
{
    return *(const bf16x8*)&s[row * 64 + ((c ^ (row & 7)) * 8)];
}

__device__ inline void mfma_ktile(const __bf16* __restrict__ sa,
                                  const __bf16* __restrict__ sb,
                                  int wm, int wn, int l15, int quad,
                                  f32x4 (&acc)[4][4])
{
#pragma unroll
    for (int kk = 0; kk < 64; kk += 32) {
        const int c8 = quad + (kk >> 3);
        bf16x8 af[4], bf[4];
#pragma unroll
        for (int i = 0; i < 4; ++i)
            af[i] = frag_read(sa, wm + i * 16 + l15, c8);
#pragma unroll
        for (int j = 0; j < 4; ++j)
            bf[j] = frag_read(sb, wn + j * 16 + l15, c8);
#pragma unroll
        for (int i = 0; i < 4; ++i)
#pragma unroll
            for (int j = 0; j < 4; ++j)
                acc[i][j] = __builtin_amdgcn_mfma_f32_16x16x32_bf16(af[i], bf[j], acc[i][j], 0, 0, 0);
    }
}

// ===========================================================================
// Deep-pipelined 128x128 projection GEMM: BK=32, 4 LDS buffers (64 KiB ->
// 2 blocks/CU), prefetch depth 3, counted vmcnt (never 0 in steady state).
// Per K-step per thread: 4 global_load_lds (2 per operand). vmcnt(12) waits
// for the stage issued 3 steps ago (its own 4 loads), leaving 12 in flight;
// the barrier then publishes (every wave verified its own quarter).
// ===========================================================================
__device__ inline void stage32(const __bf16* __restrict__ G, int ld, __bf16* s, int tid)
{
    const int r = tid >> 2;                               // 0..63
    const int c = ((tid & 3) ^ ((r >> 1) & 3)) * 8;       // swizzled source chunk
    __bf16* dst = s + (tid >> 6) * 512;                   // wave-uniform base
    gld_lds16(G + (long)r * ld + c, dst);
    gld_lds16(G + (long)(r + 64) * ld + c, dst + 2048);   // rows +64: same swizzle
}

__device__ __forceinline__ bf16x8 frag32(const __bf16* s, int row, int quad)
{
    return *(const bf16x8*)&s[row * 32 + ((quad ^ ((row >> 1) & 3)) * 8)];
}

struct Proj3 {
    const void* A[3];
    const void* W[3];
    const float* bias[3];
    __bf16* C[3];
    int vtmask;
};

__global__ __launch_bounds__(256) void gemm_proj_dp(Proj3 p)
{
    __shared__ __bf16 sA[4][128 * 32];
    __shared__ __bf16 sB[4][128 * 32];

    const int tid = threadIdx.x;
    const int L = blockIdx.x;
    const int per = gridDim.x >> 3;
    const int wrk = (L & 7) * per + (L >> 3);
    const int n0 = (wrk & 7) * 128;
    const int m0 = ((wrk >> 3) & 63) * 128;
    const int z  = wrk >> 9;
    const bool vt = (p.vtmask >> z) & 1;

    const __bf16* Ag = (const __bf16*)p.A[z] + (long)m0 * HD;
    const __bf16* Wg = (const __bf16*)p.W[z] + (long)n0 * HD;
    const float* bias = p.bias[z];
    __bf16* C = p.C[z];

    const int lane = tid & 63, l15 = lane & 15, quad = lane >> 4;
    const int wave = tid >> 6;
    const int wm = (wave >> 1) * 64;
    const int wn = (wave & 1) * 64;

    f32x4 acc[4][4];
    const f32x4 zero = {0.f, 0.f, 0.f, 0.f};
#pragma unroll
    for (int i = 0; i < 4; ++i)
#pragma unroll
        for (int j = 0; j < 4; ++j) acc[i][j] = zero;

    // prologue: stage tiles 0,1,2 (12 loads in flight)
    stage32(Ag,      HD, sA[0], tid); stage32(Wg,      HD, sB[0], tid);
    stage32(Ag + 32, HD, sA[1], tid); stage32(Wg + 32, HD, sB[1], tid);
    stage32(Ag + 64, HD, sA[2], tid); stage32(Wg + 64, HD, sB[2], tid);

    const int NT = HD / 32;   // 32
    for (int t = 0; t < NT; ++t) {
        if (t + 3 < NT) {
            stage32(Ag + (t + 3) * 32, HD, sA[(t + 3) & 3], tid);
            stage32(Wg + (t + 3) * 32, HD, sB[(t + 3) & 3], tid);
            VMC(12);                       // stage(t) landed, 12 newer in flight
        } else if (t + 2 < NT) { VMC(8); } // tail: progressively drain
        else if (t + 1 < NT)   { VMC(4); }
        else                   { VMC(0); }
        __builtin_amdgcn_s_barrier();      // publish buffer t&3
        __builtin_amdgcn_sched_barrier(0); // pin ds_reads after the barrier
        const __bf16* sa = sA[t & 3];
        const __bf16* sb = sB[t & 3];
        bf16x8 af[4], bg[4];
#pragma unroll
        for (int i = 0; i < 4; ++i) af[i] = frag32(sa, wm + i * 16 + l15, quad);
#pragma unroll
        for (int j = 0; j < 4; ++j) bg[j] = frag32(sb, wn + j * 16 + l15, quad);
        __builtin_amdgcn_s_setprio(1);
#pragma unroll
        for (int i = 0; i < 4; ++i)
#pragma unroll
            for (int j = 0; j < 4; ++j)
                acc[i][j] = __builtin_amdgcn_mfma_f32_16x16x32_bf16(af[i], bg[j], acc[i][j], 0, 0, 0);
        __builtin_amdgcn_s_setprio(0);
        __builtin_amdgcn_s_barrier();      // reads retired before buf reuse
    }

#pragma unroll
    for (int j = 0; j < 4; ++j) {
        const int col = n0 + wn + j * 16 + l15;
        const float bv = bias[col];
#pragma unroll
        for (int i = 0; i < 4; ++i) {
#pragma unroll
            for (int r = 0; r < 4; ++r) {
                const int row = m0 + wm + i * 16 + quad * 4 + r;
                const float v = acc[i][j][r] + bv;
                if (vt) {
                    C[(((long)(row >> 11) * HD) + col) * SEQ + (row & (SEQ - 1))] = (__bf16)v;
                } else {
                    C[(long)row * HD + col] = (__bf16)v;
                }
            }
        }
    }
}

// ---------------------------------------------------------------------------
// Scores GEMM, [t][s] layout: Et[t][s] = exp(<q_t,k_s>*alpha) for s<=t, else 0.
// A=qp (rows t), B=kp (rows s). TRI blocks: m0 = tb*128 (t) >= n0 = sb*128 (s).
// Row-sums (softmax denominators, per t) accumulated via shfl-reduce + atomics.
// R1 double-buffered kloop (known good).
// ---------------------------------------------------------------------------
template <typename OutT>
__global__ __launch_bounds__(256) void gemm_sc(
    const __bf16* __restrict__ A, const __bf16* __restrict__ B,
    OutT* __restrict__ C, float* __restrict__ gsum, float alpha)
{
    __shared__ __bf16 s1[2][128 * 64];
    __shared__ __bf16 s2[2][128 * 64];
    __shared__ float csum[128];

    const int tid = threadIdx.x;
    const int L = blockIdx.x;
    const int per = gridDim.x >> 3;
    const int wrk = (L & 7) * per + (L >> 3);
    const int Lt = wrk % 136;
    const int z  = wrk / 136;
    int tb = (int)((sqrtf(8.f * Lt + 1.f) - 1.f) * 0.5f);
    while ((tb + 1) * (tb + 2) / 2 <= Lt) ++tb;
    while (tb * (tb + 1) / 2 > Lt) --tb;
    const int sb = Lt - tb * (tb + 1) / 2;
    const int m0 = tb * 128;      // t (row), tb >= sb
    const int n0 = sb * 128;      // s (col)

    const __bf16* Ag = A + (long)z * SEQ * HD + (long)m0 * HD;
    const __bf16* Bg = B + (long)z * SEQ * HD + (long)n0 * HD;
    C += (long)z * SEQ * SEQ;
    gsum += (long)z * SEQ;
    if (tid < 128) csum[tid] = 0.f;    // visible after first __syncthreads

    const int lane = tid & 63, l15 = lane & 15, quad = lane >> 4;
    const int wave = tid >> 6;
    const int wm = (wave >> 1) * 64;
    const int wn = (wave & 1) * 64;

    f32x4 acc[4][4];
    const f32x4 zero = {0.f, 0.f, 0.f, 0.f};
#pragma unroll
    for (int i = 0; i < 4; ++i)
#pragma unroll
        for (int j = 0; j < 4; ++j) acc[i][j] = zero;

    stage_tile(Ag, HD, s1[0], tid);
    stage_tile(Bg, HD, s2[0], tid);
    __syncthreads();
    int cur = 0;
    for (int kc = 0; kc < HD; kc += 64) {
        const int nxt = kc + 64;
        if (nxt < HD) {
            stage_tile(Ag + nxt, HD, s1[cur ^ 1], tid);
            stage_tile(Bg + nxt, HD, s2[cur ^ 1], tid);
        }
        mfma_ktile(s1[cur], s2[cur], wm, wn, l15, quad, acc);
        __syncthreads();
        cur ^= 1;
    }

    float rsum[4][4];
#pragma unroll
    for (int i = 0; i < 4; ++i)
#pragma unroll
        for (int r = 0; r < 4; ++r) rsum[i][r] = 0.f;

#pragma unroll
    for (int j = 0; j < 4; ++j) {
        const int col = n0 + wn + j * 16 + l15;
#pragma unroll
        for (int i = 0; i < 4; ++i) {
#pragma unroll
            for (int r = 0; r < 4; ++r) {
                const int row = m0 + wm + i * 16 + quad * 4 + r;
                const float e = (col <= row) ? __expf(acc[i][j][r] * alpha) : 0.f;
                C[(long)row * SEQ + col] = (OutT)e;
                rsum[i][r] += e;
            }
        }
    }
#pragma unroll
    for (int i = 0; i < 4; ++i) {
#pragma unroll
        for (int r = 0; r < 4; ++r) {
            float v = rsum[i][r];
            v += __shfl_xor(v, 1); v += __shfl_xor(v, 2);
            v += __shfl_xor(v, 4); v += __shfl_xor(v, 8);
            if (l15 == 0) atomicAdd(&csum[wm + i * 16 + quad * 4 + r], v);
        }
    }
    __syncthreads();
    if (tid < 128) atomicAdd(&gsum[m0 + tid], csum[tid]);
}

// ---------------------------------------------------------------------------
// Context GEMM: C[t][h] = inv[t] * sum_{s<=t} Et[t][s] * vT[h][s].
// A=Et (lda=SEQ), B=vT (ldb=SEQ), causal K-limit Kend=m0+128, per-row scale
// from gsum in epilogue (one fewer bf16 rounding than the attnT pipeline).
// ---------------------------------------------------------------------------
__global__ __launch_bounds__(256) void gemm_ctx(
    const __bf16* __restrict__ A, const __bf16* __restrict__ B,
    float* __restrict__ C, const float* __restrict__ gsum)
{
    __shared__ __bf16 s1[2][128 * 64];
    __shared__ __bf16 s2[2][128 * 64];
    __shared__ float rs[128];

    const int tid = threadIdx.x;
    const int L = blockIdx.x;
    const int per = gridDim.x >> 3;
    const int wrk = (L & 7) * per + (L >> 3);
    const int n0 = (wrk & 7) * 128;          // h
    const int m0 = ((wrk >> 3) & 15) * 128;  // t
    const int z  = wrk >> 7;

    const __bf16* Ag = A + (long)z * SEQ * SEQ + (long)m0 * SEQ;
    const __bf16* Bg = B + (long)z * HD * SEQ + (long)n0 * SEQ;
    C += (long)z * SEQ * HD;
    if (tid < 128) rs[tid] = gsum[(long)z * SEQ + m0 + tid];

    const int lane = tid & 63, l15 = lane & 15, quad = lane >> 4;
    const int wave = tid >> 6;
    const int wm = (wave >> 1) * 64;
    const int wn = (wave & 1) * 64;

    f32x4 acc[4][4];
    const f32x4 zero = {0.f, 0.f, 0.f, 0.f};
#pragma unroll
    for (int i = 0; i < 4; ++i)
#pragma unroll
        for (int j = 0; j < 4; ++j) acc[i][j] = zero;

    const int Kend = m0 + 128;

    stage_tile(Ag, SEQ, s1[0], tid);
    stage_tile(Bg, SEQ, s2[0], tid);
    __syncthreads();
    int cur = 0;
    for (int kc = 0; kc < Kend; kc += 64) {
        const int nxt = kc + 64;
        if (nxt < Kend) {
            stage_tile(Ag + nxt, SEQ, s1[cur ^ 1], tid);
            stage_tile(Bg + nxt, SEQ, s2[cur ^ 1], tid);
        }
        mfma_ktile(s1[cur], s2[cur], wm, wn, l15, quad, acc);
        __syncthreads();
        cur ^= 1;
    }

    float invr[4][4];
#pragma unroll
    for (int i = 0; i < 4; ++i)
#pragma unroll
        for (int r = 0; r < 4; ++r)
            invr[i][r] = 1.0f / rs[wm + i * 16 + quad * 4 + r];

#pragma unroll
    for (int j = 0; j < 4; ++j) {
        const int col = n0 + wn + j * 16 + l15;
#pragma unroll
        for (int i = 0; i < 4; ++i) {
#pragma unroll
            for (int r = 0; r < 4; ++r) {
                const int row = m0 + wm + i * 16 + quad * 4 + r;
                C[(long)row * HD + col] = acc[i][j][r] * invr[i][r];
            }
        }
    }
}

// ---------------------------------------------------------------------------
// Emit f32 attention output: Out[s][t] = Et[t][s] * inv[t]  (Et holds 0 for
// s>t within written tiles; tiles with s0>t0+127 were never written -> zero).
// 128x128 per block, 2x2 64x64 LDS-transposed subtiles.
// ---------------------------------------------------------------------------
__global__ __launch_bounds__(256) void emit_attn(
    const __bf16* __restrict__ Et, float* __restrict__ Out,
    const float* __restrict__ csum)
{
    __shared__ float tile[64][65];
    const int b = blockIdx.z;
    const int t0 = blockIdx.x * 128;
    const int s0 = blockIdx.y * 128;
    const __bf16* Eb = Et + (long)b * SEQ * SEQ;
    float* Ob = Out + (long)b * SEQ * SEQ;
    const int tid = threadIdx.x;

    if (s0 > t0 + 127) {     // fully masked: zero-fill f32 output
        const f32x4 z4 = {0.f, 0.f, 0.f, 0.f};
        const int c4 = (tid & 31) * 4;
        for (int r = tid >> 5; r < 128; r += 8)
            *(f32x4*)&Ob[(long)(s0 + r) * SEQ + t0 + c4] = z4;
        return;
    }

#pragma unroll
    for (int dt = 0; dt < 2; ++dt) {
#pragma unroll
        for (int dsb = 0; dsb < 2; ++dsb) {
            const int tt = t0 + dt * 64, ss = s0 + dsb * 64;
            const int c4 = (tid & 15) * 4;
#pragma unroll
            for (int r0 = 0; r0 < 64; r0 += 16) {
                const int tl = r0 + (tid >> 4);
                const float inv = 1.0f / csum[(long)b * SEQ + tt + tl];
                f32x4 e = load4f(&Eb[(long)(tt + tl) * SEQ + ss + c4]);
#pragma unroll
                for (int k = 0; k < 4; ++k) tile[tl][c4 + k] = e[k] * inv;
            }
            __syncthreads();
            const int sl = tid >> 2;            // 0..63 (s-local)
            const int tc = (tid & 3) * 16;      // t-local col start
            float v[16];
#pragma unroll
            for (int jj = 0; jj < 16; ++jj) v[jj] = tile[tc + jj][sl];
#pragma unroll
            for (int q = 0; q < 4; ++q) {
                f32x4 ov;
#pragma unroll
                for (int k = 0; k < 4; ++k) ov[k] = v[q * 4 + k];
                *(f32x4*)&Ob[(long)(ss + sl) * SEQ + tt + tc + q * 4] = ov;
            }
            __syncthreads();
        }
    }
}

// ===========================================================================
// Legacy kernels (mid / fallback workspace paths) — unchanged semantics.
// ===========================================================================
template <bool TRI, bool CKLIM, bool EXPSUM, typename OutT>
__global__ __launch_bounds__(256) void gemm_bt(
    const __bf16* __restrict__ A, long strideA, int lda,
    const __bf16* __restrict__ B, long strideB, int ldb,
    OutT* __restrict__ C, long strideC, int ldc,
    float* __restrict__ gsum,
    int K, float alpha)
{
    __shared__ __bf16 sA[2][128 * 64];
    __shared__ __bf16 sB[2][128 * 64];
    __shared__ float csum[128];

    const int tid = threadIdx.x;
    const int L = blockIdx.x;
    const int per = gridDim.x >> 3;
    const int wrk = (L & 7) * per + (L >> 3);
    int n0, m0, z;
    if (TRI) {
        const int Lt = wrk % 136;
        z = wrk / 136;
        int tb = (int)((sqrtf(8.f * Lt + 1.f) - 1.f) * 0.5f);
        while ((tb + 1) * (tb + 2) / 2 <= Lt) ++tb;
        while (tb * (tb + 1) / 2 > Lt) --tb;
        const int sb = Lt - tb * (tb + 1) / 2;
        n0 = tb * 128;
        m0 = sb * 128;
    } else {
        n0 = (wrk & 7) * 128;
        m0 = ((wrk >> 3) & 15) * 128;
        z  = wrk >> 7;
    }

    const __bf16* Ag = A + (long)z * strideA + (long)m0 * lda;
    const __bf16* Bg = B + (long)z * strideB + (long)n0 * ldb;
    C += (long)z * strideC;
    if (EXPSUM) {
        gsum += (long)z * SEQ;
        if (tid < 128) csum[tid] = 0.f;
    }

    const int lane = tid & 63;
    const int l15  = lane & 15;
    const int quad = lane >> 4;
    const int wave = tid >> 6;
    const int wm = (wave >> 1) * 64;
    const int wn = (wave & 1) * 64;

    f32x4 acc[4][4];
    const f32x4 zero = {0.f, 0.f, 0.f, 0.f};
#pragma unroll
    for (int i = 0; i < 4; ++i)
#pragma unroll
        for (int j = 0; j < 4; ++j) acc[i][j] = zero;

    const int Kend = CKLIM ? min(K, m0 + 128) : K;

    stage_tile(Ag, lda, sA[0], tid);
    stage_tile(Bg, ldb, sB[0], tid);
    __syncthreads();

    int cur = 0;
    for (int kc = 0; kc < Kend; kc += 64) {
        const int nxt = kc + 64;
        if (nxt < Kend) {
            stage_tile(Ag + nxt, lda, sA[cur ^ 1], tid);
            stage_tile(Bg + nxt, ldb, sB[cur ^ 1], tid);
        }
        mfma_ktile(sA[cur], sB[cur], wm, wn, l15, quad, acc);
        __syncthreads();
        cur ^= 1;
    }

#pragma unroll
    for (int j = 0; j < 4; ++j) {
        const int col = n0 + wn + j * 16 + l15;
        float part = 0.f;
#pragma unroll
        for (int i = 0; i < 4; ++i) {
#pragma unroll
            for (int r = 0; r < 4; ++r) {
                const int row = m0 + wm + i * 16 + quad * 4 + r;
                float v = acc[i][j][r] * alpha;
                if (EXPSUM) {
                    v = __expf(v);
                    if (row <= col) part += v;
                }
                C[(long)row * ldc + col] = (OutT)v;
            }
        }
        if (EXPSUM) atomicAdd(&csum[wn + j * 16 + l15], part);
    }
    if (EXPSUM) {
        __syncthreads();
        if (tid < 128) atomicAdd(&gsum[n0 + tid], csum[tid]);
    }
}

template <typename TA, typename TW>
__global__ __launch_bounds__(256) void gemm_proj(Proj3 p)
{
    __shared__ __bf16 sA[2][128 * 64];
    __shared__ __bf16 sB[2][128 * 64];

    const int tid = threadIdx.x;
    const int L = blockIdx.x;
    const int per = gridDim.x >> 3;
    const int wrk = (L & 7) * per + (L >> 3);
    const int n0 = (wrk & 7) * 128;
    const int m0 = ((wrk >> 3) & 63) * 128;
    const int z  = wrk >> 9;
    const bool vt = (p.vtmask >> z) & 1;

    const TA* Ag = (const TA*)p.A[z] + (long)m0 * HD;
    const TW* Wg = (const TW*)p.W[z] + (long)n0 * HD;
    const float* bias = p.bias[z];
    __bf16* C = p.C[z];

    const int lane = tid & 63;
    const int l15  = lane & 15;
    const int quad = lane >> 4;
    const int wave = tid >> 6;
    const int wm = (wave >> 1) * 64;
    const int wn = (wave & 1) * 64;

    f32x4 acc[4][4];
    const f32x4 zero = {0.f, 0.f, 0.f, 0.f};
#pragma unroll
    for (int i = 0; i < 4; ++i)
#pragma unroll
        for (int j = 0; j < 4; ++j) acc[i][j] = zero;

    stage_tile(Ag, HD, sA[0], tid);
    stage_tile(Wg, HD, sB[0], tid);
    __syncthreads();

    int cur = 0;
    for (int kc = 0; kc < HD; kc += 64) {
        const int nxt = kc + 64;
        if (nxt < HD) {
            stage_tile(Ag + nxt, HD, sA[cur ^ 1], tid);
            stage_tile(Wg + nxt, HD, sB[cur ^ 1], tid);
        }
        mfma_ktile(sA[cur], sB[cur], wm, wn, l15, quad, acc);
        __syncthreads();
        cur ^= 1;
    }

#pragma unroll
    for (int j = 0; j < 4; ++j) {
        const int col = n0 + wn + j * 16 + l15;
        const float bv = bias[col];
#pragma unroll
        for (int i = 0; i < 4; ++i) {
#pragma unroll
            for (int r = 0; r < 4; ++r) {
                const int row = m0 + wm + i * 16 + quad * 4 + r;
                const float v = acc[i][j][r] + bv;
                if (vt) {
                    C[(((long)(row >> 11) * HD) + col) * SEQ + (row & (SEQ - 1))] = (__bf16)v;
                } else {
                    C[(long)row * HD + col] = (__bf16)v;
                }
            }
        }
    }
}

template <typename ET>
__global__ __launch_bounds__(256) void scale_emit(
    const ET* __restrict__ E, float* __restrict__ Out,
    const float* __restrict__ csum, __bf16* __restrict__ AT)
{
    __shared__ __bf16 tile[64][65];
    const int b = blockIdx.z;
    const int t0 = blockIdx.x * 128;
    const int s0 = blockIdx.y * 128;
    const ET* Eb = E + (long)b * SEQ * SEQ;
    float* Ob = Out + (long)b * SEQ * SEQ;
    __bf16* Ab = AT + (long)b * SEQ * SEQ;
    const int tid = threadIdx.x;

    if (s0 > t0 + 127) {
        const f32x4 z4 = {0.f, 0.f, 0.f, 0.f};
        const int c4 = (tid & 31) * 4;
        for (int r = tid >> 5; r < 128; r += 8)
            *(f32x4*)&Ob[(long)(s0 + r) * SEQ + t0 + c4] = z4;
        return;
    }

#pragma unroll
    for (int ds = 0; ds < 2; ++ds) {
#pragma unroll
        for (int dt = 0; dt < 2; ++dt) {
            const int ss = s0 + ds * 64, tt = t0 + dt * 64;
            const int c4 = (tid & 15) * 4;
            const int tcol = tt + c4;
            const f32x4 sv = *(const f32x4*)&csum[(long)b * SEQ + tcol];
            f32x4 inv;
#pragma unroll
            for (int k = 0; k < 4; ++k) inv[k] = 1.0f / sv[k];
#pragma unroll
            for (int r0 = 0; r0 < 64; r0 += 16) {
                const int s = ss + r0 + (tid >> 4);
                f32x4 e = load4f(&Eb[(long)s * SEQ + tcol]);
                f32x4 p;
#pragma unroll
                for (int k = 0; k < 4; ++k)
                    p[k] = (s <= tcol + k) ? e[k] * inv[k] : 0.f;
                *(f32x4*)&Ob[(long)s * SEQ + tcol] = p;
#pragma unroll
                for (int k = 0; k < 4; ++k)
                    tile[r0 + (tid >> 4)][c4 + k] = (__bf16)p[k];
            }
            __syncthreads();
            const int tr = tid >> 2;
            const int sc = (tid & 3) * 16;
            __bf16 v[16];
#pragma unroll
            for (int jj = 0; jj < 16; ++jj) v[jj] = tile[sc + jj][tr];
            *(bf16x8*)&Ab[(long)(tt + tr) * SEQ + ss + sc]     = *(bf16x8*)v;
            *(bf16x8*)&Ab[(long)(tt + tr) * SEQ + ss + sc + 8] = *(bf16x8*)(v + 8);
            __syncthreads();
        }
    }
}

// ---------------------------------------------------------------------------
// Batched f32 -> bf16 convert: up to 6 jobs in one dispatch.
// ---------------------------------------------------------------------------
struct CvtJob { const float* in; __bf16* out; int nblk; };
struct Cvt6 { CvtJob j[6]; };
__global__ __launch_bounds__(256) void cvt_bf16(Cvt6 c)
{
    const CvtJob jb = c.j[blockIdx.y];
    if ((int)blockIdx.x >= jb.nblk) return;
    const long i = ((long)blockIdx.x * 256 + threadIdx.x) * 8;
    *(bf16x8*)&jb.out[i] = load8cvt(&jb.in[i]);
}

// ---------------------------------------------------------------------------
extern "C" void kernel_launch(void* const* d_in, const int* in_sizes, int n_in,
                              void* d_out, int out_size, void* d_ws, size_t ws_size,
                              hipStream_t stream)
{
    const float* queries = (const float*)d_in[0];
    const float* keys    = (const float*)d_in[1];
    const float* values  = (const float*)d_in[2];
    const float* Wq = (const float*)d_in[3];
    const float* bq = (const float*)d_in[4];
    const float* Wk = (const float*)d_in[5];
    const float* bk = (const float*)d_in[6];
    const float* Wv = (const float*)d_in[7];
    const float* bv = (const float*)d_in[8];

    const long tokens = (long)NB * SEQ;           // 8192
    const long pe = tokens * HD;                  // elems per 16 MiB buffer
    const size_t SLOT = (size_t)pe * sizeof(__bf16);   // 16 MiB
    const int ABLK = (int)(pe / 2048);            // 4096 cvt blocks per activation
    const int WBLK = WEL / 2048;                  // 512 cvt blocks per weight

    float* outCtx  = (float*)d_out;               // [4][2048][1024] f32
    float* outAttn = outCtx + tokens * HD;        // [4][2048][2048] f32
    __bf16* wb = (__bf16*)outAttn;                // bf16 weights: dead-at-start
    __bf16* Wqb = wb, *Wkb = wb + WEL, *Wvb = wb + 2 * WEL;

    const dim3 blk(256);
    char* w = (char*)d_ws;
    __bf16 *qp, *kp, *vT;

    if (ws_size >= 6 * SLOT) {
        // [xq][xk][xv][qp][kp][vT]; after proj: Et bf16 -> slots 0-1,
        // colsum -> slot 2 (xv dead), vT slot 5 stays live.
        __bf16* xq = (__bf16*)w;
        __bf16* xk = (__bf16*)(w + SLOT);
        __bf16* xv = (__bf16*)(w + 2 * SLOT);
        qp = (__bf16*)(w + 3 * SLOT);
        kp = (__bf16*)(w + 4 * SLOT);
        vT = (__bf16*)(w + 5 * SLOT);
        __bf16* Ebf = (__bf16*)w;
        float* colsum = (float*)(w + 2 * SLOT);

        Cvt6 cv = {{{queries, xq, ABLK}, {keys, xk, ABLK}, {values, xv, ABLK},
                    {Wq, Wqb, WBLK}, {Wk, Wkb, WBLK}, {Wv, Wvb, WBLK}}};
        cvt_bf16<<<dim3(ABLK, 6), blk, 0, stream>>>(cv);
        Proj3 pj = {{xq, xk, xv}, {Wqb, Wkb, Wvb}, {bq, bk, bv}, {qp, kp, vT}, 4};
        gemm_proj_dp<<<dim3(512 * 3), blk, 0, stream>>>(pj);

        hipMemsetAsync(colsum, 0, (size_t)NB * SEQ * sizeof(float), stream);
        // Et[b][t][s] = exp(<q_t,k_s>/32) masked; rowsums into colsum
        gemm_sc<__bf16><<<dim3(544), blk, 0, stream>>>(qp, kp, Ebf, colsum, 0.03125f);
        // f32 attn output (transposed, normalized)
        emit_attn<<<dim3(SEQ / 128, SEQ / 128, NB), blk, 0, stream>>>(
            Ebf, outAttn, colsum);
        // context with per-row normalization in epilogue
        gemm_ctx<<<dim3(512), blk, 0, stream>>>(Ebf, vT, outCtx, colsum);
    } else if (ws_size >= 4 * SLOT) {
        // legacy mid path: [x0][qp][kp][x1->vT]; attnT aliases x0+qp;
        // E stays f32 in outAttn (in-place scale_emit).
        float* colsum = outCtx;
        hipMemsetAsync(colsum, 0, (size_t)NB * SEQ * sizeof(float), stream);
        __bf16* x0 = (__bf16*)w;
        qp = (__bf16*)(w + SLOT);
        kp = (__bf16*)(w + 2 * SLOT);
        __bf16* x1 = (__bf16*)(w + 3 * SLOT);
        vT = x1;
        __bf16* attnT = (__bf16*)d_ws;

        Cvt6 cv = {{{queries, x0, ABLK}, {keys, x1, ABLK},
                    {Wq, Wqb, WBLK}, {Wk, Wkb, WBLK}, {Wv, Wvb, WBLK},
                    {nullptr, nullptr, 0}}};
        cvt_bf16<<<dim3(ABLK, 5), blk, 0, stream>>>(cv);
        Proj3 pqk = {{x0, x1, nullptr}, {Wqb, Wkb, nullptr}, {bq, bk, nullptr},
                     {qp, kp, nullptr}, 0};
        gemm_proj_dp<<<dim3(512 * 2), blk, 0, stream>>>(pqk);
        Cvt6 cvv = {{{values, x0, ABLK}, {nullptr, nullptr, 0}, {nullptr, nullptr, 0},
                     {nullptr, nullptr, 0}, {nullptr, nullptr, 0}, {nullptr, nullptr, 0}}};
        cvt_bf16<<<dim3(ABLK, 1), blk, 0, stream>>>(cvv);
        Proj3 pv = {{x0, nullptr, nullptr}, {Wvb, nullptr, nullptr},
                    {bv, nullptr, nullptr}, {vT, nullptr, nullptr}, 1};
        gemm_proj_dp<<<dim3(512), blk, 0, stream>>>(pv);

        gemm_bt<true, false, true, float><<<dim3(544), blk, 0, stream>>>(
            kp, (long)SEQ * HD, HD, qp, (long)SEQ * HD, HD,
            outAttn, (long)SEQ * SEQ, SEQ, colsum, HD, 0.03125f);
        scale_emit<float><<<dim3(SEQ / 128, SEQ / 128, NB), blk, 0, stream>>>(
            outAttn, outAttn, colsum, attnT);
        gemm_bt<false, true, false, float><<<dim3(512), blk, 0, stream>>>(
            attnT, (long)SEQ * SEQ, SEQ, vT, (long)HD * SEQ, SEQ,
            outCtx, (long)SEQ * HD, HD, nullptr, SEQ, 1.0f);
    } else {
        // fallback: f32-staged operands straight from inputs; [qp][kp][vT]
        float* colsum = outCtx;
        hipMemsetAsync(colsum, 0, (size_t)NB * SEQ * sizeof(float), stream);
        qp = (__bf16*)w;
        kp = (__bf16*)(w + SLOT);
        vT = (__bf16*)(w + 2 * SLOT);
        __bf16* attnT = (__bf16*)d_ws;
        Proj3 pj = {{queries, keys, values}, {Wq, Wk, Wv}, {bq, bk, bv},
                    {qp, kp, vT}, 4};
        gemm_proj<float, float><<<dim3(512 * 3), blk, 0, stream>>>(pj);

        gemm_bt<true, false, true, float><<<dim3(544), blk, 0, stream>>>(
            kp, (long)SEQ * HD, HD, qp, (long)SEQ * HD, HD,
            outAttn, (long)SEQ * SEQ, SEQ, colsum, HD, 0.03125f);
        scale_emit<float><<<dim3(SEQ / 128, SEQ / 128, NB), blk, 0, stream>>>(
            outAttn, outAttn, colsum, attnT);
        gemm_bt<false, true, false, float><<<dim3(512), blk, 0, stream>>>(
            attnT, (long)SEQ * SEQ, SEQ, vT, (long)HD * SEQ, SEQ,
            outCtx, (long)SEQ * HD, HD, nullptr, SEQ, 1.0f);
    }
}

// Round 5
// 376.647 us; speedup vs baseline: 1.0606x; 1.0606x over previous
//
#include <hip/hip_runtime.h>
#include <math.h>

typedef __bf16 bf16x8 __attribute__((ext_vector_type(8)));
typedef __bf16 bf16x4 __attribute__((ext_vector_type(4)));
typedef float f32x4 __attribute__((ext_vector_type(4)));

#define HD 1024
#define SEQ 2048
#define NB 4
#define WEL (HD * HD)   // elements per weight matrix

// Load 8 contiguous elements as bf16x8, converting f32 -> bf16 if needed.
__device__ inline bf16x8 load8cvt(const __bf16* p) { return *(const bf16x8*)p; }
__device__ inline bf16x8 load8cvt(const float* p) {
    f32x4 a = *(const f32x4*)p;
    f32x4 b = *(const f32x4*)(p + 4);
    bf16x8 r;
#pragma unroll
    for (int i = 0; i < 4; ++i) { r[i] = (__bf16)a[i]; r[i + 4] = (__bf16)b[i]; }
    return r;
}

// Load 4 contiguous elements as f32x4 (from f32 or bf16 source).
__device__ inline f32x4 load4f(const float* p) { return *(const f32x4*)p; }
__device__ inline f32x4 load4f(const __bf16* p) {
    bf16x4 v = *(const bf16x4*)p;
    f32x4 r;
#pragma unroll
    for (int i = 0; i < 4; ++i) r[i] = (float)v[i];
    return r;
}

// Async global->LDS, 16 bytes per lane (global_load_lds_dwordx4).
__device__ inline void gld_lds16(const void* g, void* l) {
    __builtin_amdgcn_global_load_lds(
        (const __attribute__((address_space(1))) unsigned int*)g,
        (__attribute__((address_space(3))) unsigned int*)l, 16, 0, 0);
}

// ===========================================================================
// 128x128 BK=64 tile machinery (shared by all GEMMs). XOR-swizzled LDS tile:
// LDS chunk (row, j) holds GLOBAL chunk (row, j ^ (row&7)); global source is
// pre-swizzled so the LDS destination stays linear (global_load_lds rule).
// ===========================================================================
template <typename T>
__device__ inline void stage_tile(const T* __restrict__ G, int ld, __bf16* s, int tid)
{
    const int r  = tid >> 3;                          // 0..31
    const int co = ((tid & 7) ^ (r & 7)) * 8;         // swizzled source column
    if constexpr (sizeof(T) == 2) {
        __bf16* dst = s + (tid >> 6) * 512;           // wave-uniform base
#pragma unroll
        for (int c = 0; c < 4; ++c)
            gld_lds16(G + (long)(c * 32 + r) * ld + co, dst + c * 2048);
    } else {
#pragma unroll
        for (int c = 0; c < 4; ++c)
            *(bf16x8*)(s + c * 2048 + tid * 8) = load8cvt(G + (long)(c * 32 + r) * ld + co);
    }
}

__device__ inline bf16x8 frag_read(const __bf16* s, int row, int c)
{
    return *(const bf16x8*)&s[row * 64 + ((c ^ (row & 7)) * 8)];
}

__device__ inline void mfma_ktile(const __bf16* __restrict__ sa,
                                  const __bf16* __restrict__ sb,
                                  int wm, int wn, int l15, int quad,
                                  f32x4 (&acc)[4][4])
{
#pragma unroll
    for (int kk = 0; kk < 64; kk += 32) {
        const int c8 = quad + (kk >> 3);
        bf16x8 af[4], bf[4];
#pragma unroll
        for (int i = 0; i < 4; ++i)
            af[i] = frag_read(sa, wm + i * 16 + l15, c8);
#pragma unroll
        for (int j = 0; j < 4; ++j)
            bf[j] = frag_read(sb, wn + j * 16 + l15, c8);
#pragma unroll
        for (int i = 0; i < 4; ++i)
#pragma unroll
            for (int j = 0; j < 4; ++j)
                acc[i][j] = __builtin_amdgcn_mfma_f32_16x16x32_bf16(af[i], bf[j], acc[i][j], 0, 0, 0);
    }
}

// ===========================================================================
// Projection GEMM (R1 double-buffered structure — best measured: 103.2 us).
// Z-batched: C_z[m,n] = sum_k A_z[m,k]*W_z[n,k] + bias_z[n]; vtmask bit z =>
// transposed scatter-store vT[b][n][s]. Grid 512*nz, XCD-remapped.
// ===========================================================================
struct Proj3 {
    const void* A[3];
    const void* W[3];
    const float* bias[3];
    __bf16* C[3];
    int vtmask;
};

template <typename TA, typename TW>
__global__ __launch_bounds__(256) void gemm_proj(Proj3 p)
{
    __shared__ __bf16 sA[2][128 * 64];
    __shared__ __bf16 sB[2][128 * 64];

    const int tid = threadIdx.x;
    const int L = blockIdx.x;
    const int per = gridDim.x >> 3;
    const int wrk = (L & 7) * per + (L >> 3);
    const int n0 = (wrk & 7) * 128;
    const int m0 = ((wrk >> 3) & 63) * 128;
    const int z  = wrk >> 9;
    const bool vt = (p.vtmask >> z) & 1;

    const TA* Ag = (const TA*)p.A[z] + (long)m0 * HD;
    const TW* Wg = (const TW*)p.W[z] + (long)n0 * HD;
    const float* bias = p.bias[z];
    __bf16* C = p.C[z];

    const int lane = tid & 63;
    const int l15  = lane & 15;
    const int quad = lane >> 4;
    const int wave = tid >> 6;
    const int wm = (wave >> 1) * 64;
    const int wn = (wave & 1) * 64;

    f32x4 acc[4][4];
    const f32x4 zero = {0.f, 0.f, 0.f, 0.f};
#pragma unroll
    for (int i = 0; i < 4; ++i)
#pragma unroll
        for (int j = 0; j < 4; ++j) acc[i][j] = zero;

    stage_tile(Ag, HD, sA[0], tid);
    stage_tile(Wg, HD, sB[0], tid);
    __syncthreads();

    int cur = 0;
    for (int kc = 0; kc < HD; kc += 64) {
        const int nxt = kc + 64;
        if (nxt < HD) {                       // issue next tile's loads first
            stage_tile(Ag + nxt, HD, sA[cur ^ 1], tid);
            stage_tile(Wg + nxt, HD, sB[cur ^ 1], tid);
        }
        mfma_ktile(sA[cur], sB[cur], wm, wn, l15, quad, acc);
        __syncthreads();
        cur ^= 1;
    }

#pragma unroll
    for (int j = 0; j < 4; ++j) {
        const int col = n0 + wn + j * 16 + l15;
        const float bv = bias[col];
#pragma unroll
        for (int i = 0; i < 4; ++i) {
#pragma unroll
            for (int r = 0; r < 4; ++r) {
                const int row = m0 + wm + i * 16 + quad * 4 + r;
                const float v = acc[i][j][r] + bv;
                if (vt) {
                    C[(((long)(row >> 11) * HD) + col) * SEQ + (row & (SEQ - 1))] = (__bf16)v;
                } else {
                    C[(long)row * HD + col] = (__bf16)v;
                }
            }
        }
    }
}

// ---------------------------------------------------------------------------
// Scores GEMM, [t][s] layout: Et[t][s] = exp(<q_t,k_s>*alpha) for s<=t, else 0.
// A=qp (rows t), B=kp (rows s). TRI blocks: m0 = tb*128 (t) >= n0 = sb*128 (s).
// Row-sums (softmax denominators, per t) accumulated via shfl-reduce + atomics.
// ---------------------------------------------------------------------------
template <typename OutT>
__global__ __launch_bounds__(256) void gemm_sc(
    const __bf16* __restrict__ A, const __bf16* __restrict__ B,
    OutT* __restrict__ C, float* __restrict__ gsum, float alpha)
{
    __shared__ __bf16 s1[2][128 * 64];
    __shared__ __bf16 s2[2][128 * 64];
    __shared__ float csum[128];

    const int tid = threadIdx.x;
    const int L = blockIdx.x;
    const int per = gridDim.x >> 3;
    const int wrk = (L & 7) * per + (L >> 3);
    const int Lt = wrk % 136;
    const int z  = wrk / 136;
    int tb = (int)((sqrtf(8.f * Lt + 1.f) - 1.f) * 0.5f);
    while ((tb + 1) * (tb + 2) / 2 <= Lt) ++tb;
    while (tb * (tb + 1) / 2 > Lt) --tb;
    const int sb = Lt - tb * (tb + 1) / 2;
    const int m0 = tb * 128;      // t (row), tb >= sb
    const int n0 = sb * 128;      // s (col)

    const __bf16* Ag = A + (long)z * SEQ * HD + (long)m0 * HD;
    const __bf16* Bg = B + (long)z * SEQ * HD + (long)n0 * HD;
    C += (long)z * SEQ * SEQ;
    gsum += (long)z * SEQ;
    if (tid < 128) csum[tid] = 0.f;    // visible after first __syncthreads

    const int lane = tid & 63, l15 = lane & 15, quad = lane >> 4;
    const int wave = tid >> 6;
    const int wm = (wave >> 1) * 64;
    const int wn = (wave & 1) * 64;

    f32x4 acc[4][4];
    const f32x4 zero = {0.f, 0.f, 0.f, 0.f};
#pragma unroll
    for (int i = 0; i < 4; ++i)
#pragma unroll
        for (int j = 0; j < 4; ++j) acc[i][j] = zero;

    stage_tile(Ag, HD, s1[0], tid);
    stage_tile(Bg, HD, s2[0], tid);
    __syncthreads();
    int cur = 0;
    for (int kc = 0; kc < HD; kc += 64) {
        const int nxt = kc + 64;
        if (nxt < HD) {
            stage_tile(Ag + nxt, HD, s1[cur ^ 1], tid);
            stage_tile(Bg + nxt, HD, s2[cur ^ 1], tid);
        }
        mfma_ktile(s1[cur], s2[cur], wm, wn, l15, quad, acc);
        __syncthreads();
        cur ^= 1;
    }

    float rsum[4][4];
#pragma unroll
    for (int i = 0; i < 4; ++i)
#pragma unroll
        for (int r = 0; r < 4; ++r) rsum[i][r] = 0.f;

#pragma unroll
    for (int j = 0; j < 4; ++j) {
        const int col = n0 + wn + j * 16 + l15;
#pragma unroll
        for (int i = 0; i < 4; ++i) {
#pragma unroll
            for (int r = 0; r < 4; ++r) {
                const int row = m0 + wm + i * 16 + quad * 4 + r;
                const float e = (col <= row) ? __expf(acc[i][j][r] * alpha) : 0.f;
                C[(long)row * SEQ + col] = (OutT)e;
                rsum[i][r] += e;
            }
        }
    }
#pragma unroll
    for (int i = 0; i < 4; ++i) {
#pragma unroll
        for (int r = 0; r < 4; ++r) {
            float v = rsum[i][r];
            v += __shfl_xor(v, 1); v += __shfl_xor(v, 2);
            v += __shfl_xor(v, 4); v += __shfl_xor(v, 8);
            if (l15 == 0) atomicAdd(&csum[wm + i * 16 + quad * 4 + r], v);
        }
    }
    __syncthreads();
    if (tid < 128) atomicAdd(&gsum[m0 + tid], csum[tid]);
}

// ---------------------------------------------------------------------------
// Context GEMM: C[t][h] = inv[t] * sum_{s<=t} Et[t][s] * vT[h][s].
// A=Et (lda=SEQ), B=vT (ldb=SEQ), causal K-limit Kend=m0+128, per-row scale
// from gsum in epilogue. m-block index goes through the pairing bijection
// 0,15,1,14,... so consecutively-dispatched blocks pair long+short K (each
// adjacent pair sums to a uniform 2176 K-rows) -> balanced CU residency.
// ---------------------------------------------------------------------------
__global__ __launch_bounds__(256) void gemm_ctx(
    const __bf16* __restrict__ A, const __bf16* __restrict__ B,
    float* __restrict__ C, const float* __restrict__ gsum)
{
    __shared__ __bf16 s1[2][128 * 64];
    __shared__ __bf16 s2[2][128 * 64];
    __shared__ float rs[128];

    const int tid = threadIdx.x;
    const int L = blockIdx.x;
    const int per = gridDim.x >> 3;
    const int wrk = (L & 7) * per + (L >> 3);
    const int n0 = (wrk & 7) * 128;          // h
    const int q  = (wrk >> 3) & 15;
    const int mb = (q & 1) ? (15 - (q >> 1)) : (q >> 1);   // 0,15,1,14,...
    const int m0 = mb * 128;                 // t
    const int z  = wrk >> 7;

    const __bf16* Ag = A + (long)z * SEQ * SEQ + (long)m0 * SEQ;
    const __bf16* Bg = B + (long)z * HD * SEQ + (long)n0 * SEQ;
    C += (long)z * SEQ * HD;
    if (tid < 128) rs[tid] = gsum[(long)z * SEQ + m0 + tid];

    const int lane = tid & 63, l15 = lane & 15, quad = lane >> 4;
    const int wave = tid >> 6;
    const int wm = (wave >> 1) * 64;
    const int wn = (wave & 1) * 64;

    f32x4 acc[4][4];
    const f32x4 zero = {0.f, 0.f, 0.f, 0.f};
#pragma unroll
    for (int i = 0; i < 4; ++i)
#pragma unroll
        for (int j = 0; j < 4; ++j) acc[i][j] = zero;

    const int Kend = m0 + 128;

    stage_tile(Ag, SEQ, s1[0], tid);
    stage_tile(Bg, SEQ, s2[0], tid);
    __syncthreads();
    int cur = 0;
    for (int kc = 0; kc < Kend; kc += 64) {
        const int nxt = kc + 64;
        if (nxt < Kend) {
            stage_tile(Ag + nxt, SEQ, s1[cur ^ 1], tid);
            stage_tile(Bg + nxt, SEQ, s2[cur ^ 1], tid);
        }
        mfma_ktile(s1[cur], s2[cur], wm, wn, l15, quad, acc);
        __syncthreads();
        cur ^= 1;
    }

    float invr[4][4];
#pragma unroll
    for (int i = 0; i < 4; ++i)
#pragma unroll
        for (int r = 0; r < 4; ++r)
            invr[i][r] = 1.0f / rs[wm + i * 16 + quad * 4 + r];

#pragma unroll
    for (int j = 0; j < 4; ++j) {
        const int col = n0 + wn + j * 16 + l15;
#pragma unroll
        for (int i = 0; i < 4; ++i) {
#pragma unroll
            for (int r = 0; r < 4; ++r) {
                const int row = m0 + wm + i * 16 + quad * 4 + r;
                C[(long)row * HD + col] = acc[i][j][r] * invr[i][r];
            }
        }
    }
}

// ---------------------------------------------------------------------------
// Emit f32 attention output: Out[s][t] = Et[t][s] * inv[t]. 128x128 per block,
// 2x2 64x64 LDS-transposed subtiles; tile padded to [64][68] so both the
// row-major writes and the transposed reads are ~2-way bank aliased (free);
// global stores arranged so each 4-lane cluster writes 64B contiguous.
// ---------------------------------------------------------------------------
__global__ __launch_bounds__(256) void emit_attn(
    const __bf16* __restrict__ Et, float* __restrict__ Out,
    const float* __restrict__ csum)
{
    __shared__ float tile[64][68];
    const int b = blockIdx.z;
    const int t0 = blockIdx.x * 128;
    const int s0 = blockIdx.y * 128;
    const __bf16* Eb = Et + (long)b * SEQ * SEQ;
    float* Ob = Out + (long)b * SEQ * SEQ;
    const int tid = threadIdx.x;

    if (s0 > t0 + 127) {     // fully masked: zero-fill f32 output
        const f32x4 z4 = {0.f, 0.f, 0.f, 0.f};
        const int c4 = (tid & 31) * 4;
        for (int r = tid >> 5; r < 128; r += 8)
            *(f32x4*)&Ob[(long)(s0 + r) * SEQ + t0 + c4] = z4;
        return;
    }

#pragma unroll
    for (int dt = 0; dt < 2; ++dt) {
#pragma unroll
        for (int dsb = 0; dsb < 2; ++dsb) {
            const int tt = t0 + dt * 64, ss = s0 + dsb * 64;
            const int c4 = (tid & 15) * 4;
#pragma unroll
            for (int r0 = 0; r0 < 64; r0 += 16) {
                const int tl = r0 + (tid >> 4);
                const float inv = 1.0f / csum[(long)b * SEQ + tt + tl];
                f32x4 e = load4f(&Eb[(long)(tt + tl) * SEQ + ss + c4]);
#pragma unroll
                for (int k = 0; k < 4; ++k) tile[tl][c4 + k] = e[k] * inv;
            }
            __syncthreads();
            const int sl = tid >> 2;            // 0..63 (s-local row)
            const int t4 = (tid & 3) * 4;       // cluster offset within 16-col group
#pragma unroll
            for (int qq = 0; qq < 4; ++qq) {
                f32x4 ov;
#pragma unroll
                for (int k = 0; k < 4; ++k) ov[k] = tile[qq * 16 + t4 + k][sl];
                *(f32x4*)&Ob[(long)(ss + sl) * SEQ + tt + qq * 16 + t4] = ov;
            }
            __syncthreads();
        }
    }
}

// ===========================================================================
// Legacy kernels (mid / fallback workspace paths) — unchanged semantics.
// ===========================================================================
template <bool TRI, bool CKLIM, bool EXPSUM, typename OutT>
__global__ __launch_bounds__(256) void gemm_bt(
    const __bf16* __restrict__ A, long strideA, int lda,
    const __bf16* __restrict__ B, long strideB, int ldb,
    OutT* __restrict__ C, long strideC, int ldc,
    float* __restrict__ gsum,
    int K, float alpha)
{
    __shared__ __bf16 sA[2][128 * 64];
    __shared__ __bf16 sB[2][128 * 64];
    __shared__ float csum[128];

    const int tid = threadIdx.x;
    const int L = blockIdx.x;
    const int per = gridDim.x >> 3;
    const int wrk = (L & 7) * per + (L >> 3);
    int n0, m0, z;
    if (TRI) {
        const int Lt = wrk % 136;
        z = wrk / 136;
        int tb = (int)((sqrtf(8.f * Lt + 1.f) - 1.f) * 0.5f);
        while ((tb + 1) * (tb + 2) / 2 <= Lt) ++tb;
        while (tb * (tb + 1) / 2 > Lt) --tb;
        const int sb = Lt - tb * (tb + 1) / 2;
        n0 = tb * 128;
        m0 = sb * 128;
    } else {
        n0 = (wrk & 7) * 128;
        m0 = ((wrk >> 3) & 15) * 128;
        z  = wrk >> 7;
    }

    const __bf16* Ag = A + (long)z * strideA + (long)m0 * lda;
    const __bf16* Bg = B + (long)z * strideB + (long)n0 * ldb;
    C += (long)z * strideC;
    if (EXPSUM) {
        gsum += (long)z * SEQ;
        if (tid < 128) csum[tid] = 0.f;
    }

    const int lane = tid & 63;
    const int l15  = lane & 15;
    const int quad = lane >> 4;
    const int wave = tid >> 6;
    const int wm = (wave >> 1) * 64;
    const int wn = (wave & 1) * 64;

    f32x4 acc[4][4];
    const f32x4 zero = {0.f, 0.f, 0.f, 0.f};
#pragma unroll
    for (int i = 0; i < 4; ++i)
#pragma unroll
        for (int j = 0; j < 4; ++j) acc[i][j] = zero;

    const int Kend = CKLIM ? min(K, m0 + 128) : K;

    stage_tile(Ag, lda, sA[0], tid);
    stage_tile(Bg, ldb, sB[0], tid);
    __syncthreads();

    int cur = 0;
    for (int kc = 0; kc < Kend; kc += 64) {
        const int nxt = kc + 64;
        if (nxt < Kend) {
            stage_tile(Ag + nxt, lda, sA[cur ^ 1], tid);
            stage_tile(Bg + nxt, ldb, sB[cur ^ 1], tid);
        }
        mfma_ktile(sA[cur], sB[cur], wm, wn, l15, quad, acc);
        __syncthreads();
        cur ^= 1;
    }

#pragma unroll
    for (int j = 0; j < 4; ++j) {
        const int col = n0 + wn + j * 16 + l15;
        float part = 0.f;
#pragma unroll
        for (int i = 0; i < 4; ++i) {
#pragma unroll
            for (int r = 0; r < 4; ++r) {
                const int row = m0 + wm + i * 16 + quad * 4 + r;
                float v = acc[i][j][r] * alpha;
                if (EXPSUM) {
                    v = __expf(v);
                    if (row <= col) part += v;
                }
                C[(long)row * ldc + col] = (OutT)v;
            }
        }
        if (EXPSUM) atomicAdd(&csum[wn + j * 16 + l15], part);
    }
    if (EXPSUM) {
        __syncthreads();
        if (tid < 128) atomicAdd(&gsum[n0 + tid], csum[tid]);
    }
}

template <typename ET>
__global__ __launch_bounds__(256) void scale_emit(
    const ET* __restrict__ E, float* __restrict__ Out,
    const float* __restrict__ csum, __bf16* __restrict__ AT)
{
    __shared__ __bf16 tile[64][65];
    const int b = blockIdx.z;
    const int t0 = blockIdx.x * 128;
    const int s0 = blockIdx.y * 128;
    const ET* Eb = E + (long)b * SEQ * SEQ;
    float* Ob = Out + (long)b * SEQ * SEQ;
    __bf16* Ab = AT + (long)b * SEQ * SEQ;
    const int tid = threadIdx.x;

    if (s0 > t0 + 127) {
        const f32x4 z4 = {0.f, 0.f, 0.f, 0.f};
        const int c4 = (tid & 31) * 4;
        for (int r = tid >> 5; r < 128; r += 8)
            *(f32x4*)&Ob[(long)(s0 + r) * SEQ + t0 + c4] = z4;
        return;
    }

#pragma unroll
    for (int ds = 0; ds < 2; ++ds) {
#pragma unroll
        for (int dt = 0; dt < 2; ++dt) {
            const int ss = s0 + ds * 64, tt = t0 + dt * 64;
            const int c4 = (tid & 15) * 4;
            const int tcol = tt + c4;
            const f32x4 sv = *(const f32x4*)&csum[(long)b * SEQ + tcol];
            f32x4 inv;
#pragma unroll
            for (int k = 0; k < 4; ++k) inv[k] = 1.0f / sv[k];
#pragma unroll
            for (int r0 = 0; r0 < 64; r0 += 16) {
                const int s = ss + r0 + (tid >> 4);
                f32x4 e = load4f(&Eb[(long)s * SEQ + tcol]);
                f32x4 p;
#pragma unroll
                for (int k = 0; k < 4; ++k)
                    p[k] = (s <= tcol + k) ? e[k] * inv[k] : 0.f;
                *(f32x4*)&Ob[(long)s * SEQ + tcol] = p;
#pragma unroll
                for (int k = 0; k < 4; ++k)
                    tile[r0 + (tid >> 4)][c4 + k] = (__bf16)p[k];
            }
            __syncthreads();
            const int tr = tid >> 2;
            const int sc = (tid & 3) * 16;
            __bf16 v[16];
#pragma unroll
            for (int jj = 0; jj < 16; ++jj) v[jj] = tile[sc + jj][tr];
            *(bf16x8*)&Ab[(long)(tt + tr) * SEQ + ss + sc]     = *(bf16x8*)v;
            *(bf16x8*)&Ab[(long)(tt + tr) * SEQ + ss + sc + 8] = *(bf16x8*)(v + 8);
            __syncthreads();
        }
    }
}

// ---------------------------------------------------------------------------
// Batched f32 -> bf16 convert: up to 6 jobs in one dispatch.
// ---------------------------------------------------------------------------
struct CvtJob { const float* in; __bf16* out; int nblk; };
struct Cvt6 { CvtJob j[6]; };
__global__ __launch_bounds__(256) void cvt_bf16(Cvt6 c)
{
    const CvtJob jb = c.j[blockIdx.y];
    if ((int)blockIdx.x >= jb.nblk) return;
    const long i = ((long)blockIdx.x * 256 + threadIdx.x) * 8;
    *(bf16x8*)&jb.out[i] = load8cvt(&jb.in[i]);
}

// ---------------------------------------------------------------------------
extern "C" void kernel_launch(void* const* d_in, const int* in_sizes, int n_in,
                              void* d_out, int out_size, void* d_ws, size_t ws_size,
                              hipStream_t stream)
{
    const float* queries = (const float*)d_in[0];
    const float* keys    = (const float*)d_in[1];
    const float* values  = (const float*)d_in[2];
    const float* Wq = (const float*)d_in[3];
    const float* bq = (const float*)d_in[4];
    const float* Wk = (const float*)d_in[5];
    const float* bk = (const float*)d_in[6];
    const float* Wv = (const float*)d_in[7];
    const float* bv = (const float*)d_in[8];

    const long tokens = (long)NB * SEQ;           // 8192
    const long pe = tokens * HD;                  // elems per 16 MiB buffer
    const size_t SLOT = (size_t)pe * sizeof(__bf16);   // 16 MiB
    const int ABLK = (int)(pe / 2048);            // 4096 cvt blocks per activation
    const int WBLK = WEL / 2048;                  // 512 cvt blocks per weight

    float* outCtx  = (float*)d_out;               // [4][2048][1024] f32
    float* outAttn = outCtx + tokens * HD;        // [4][2048][2048] f32
    __bf16* wb = (__bf16*)outAttn;                // bf16 weights: dead-at-start
    __bf16* Wqb = wb, *Wkb = wb + WEL, *Wvb = wb + 2 * WEL;

    const dim3 blk(256);
    char* w = (char*)d_ws;
    __bf16 *qp, *kp, *vT;

    if (ws_size >= 6 * SLOT) {
        // [xq][xk][xv][qp][kp][vT]; after proj: Et bf16 -> slots 0-1,
        // colsum -> slot 2 (xv dead), vT slot 5 stays live.
        __bf16* xq = (__bf16*)w;
        __bf16* xk = (__bf16*)(w + SLOT);
        __bf16* xv = (__bf16*)(w + 2 * SLOT);
        qp = (__bf16*)(w + 3 * SLOT);
        kp = (__bf16*)(w + 4 * SLOT);
        vT = (__bf16*)(w + 5 * SLOT);
        __bf16* Ebf = (__bf16*)w;
        float* colsum = (float*)(w + 2 * SLOT);

        Cvt6 cv = {{{queries, xq, ABLK}, {keys, xk, ABLK}, {values, xv, ABLK},
                    {Wq, Wqb, WBLK}, {Wk, Wkb, WBLK}, {Wv, Wvb, WBLK}}};
        cvt_bf16<<<dim3(ABLK, 6), blk, 0, stream>>>(cv);
        Proj3 pj = {{xq, xk, xv}, {Wqb, Wkb, Wvb}, {bq, bk, bv}, {qp, kp, vT}, 4};
        gemm_proj<__bf16, __bf16><<<dim3(512 * 3), blk, 0, stream>>>(pj);

        hipMemsetAsync(colsum, 0, (size_t)NB * SEQ * sizeof(float), stream);
        // Et[b][t][s] = exp(<q_t,k_s>/32) masked; rowsums into colsum
        gemm_sc<__bf16><<<dim3(544), blk, 0, stream>>>(qp, kp, Ebf, colsum, 0.03125f);
        // f32 attn output (transposed, normalized)
        emit_attn<<<dim3(SEQ / 128, SEQ / 128, NB), blk, 0, stream>>>(
            Ebf, outAttn, colsum);
        // context with per-row normalization in epilogue
        gemm_ctx<<<dim3(512), blk, 0, stream>>>(Ebf, vT, outCtx, colsum);
    } else if (ws_size >= 4 * SLOT) {
        // legacy mid path: [x0][qp][kp][x1->vT]; attnT aliases x0+qp;
        // E stays f32 in outAttn (in-place scale_emit).
        float* colsum = outCtx;
        hipMemsetAsync(colsum, 0, (size_t)NB * SEQ * sizeof(float), stream);
        __bf16* x0 = (__bf16*)w;
        qp = (__bf16*)(w + SLOT);
        kp = (__bf16*)(w + 2 * SLOT);
        __bf16* x1 = (__bf16*)(w + 3 * SLOT);
        vT = x1;
        __bf16* attnT = (__bf16*)d_ws;

        Cvt6 cv = {{{queries, x0, ABLK}, {keys, x1, ABLK},
                    {Wq, Wqb, WBLK}, {Wk, Wkb, WBLK}, {Wv, Wvb, WBLK},
                    {nullptr, nullptr, 0}}};
        cvt_bf16<<<dim3(ABLK, 5), blk, 0, stream>>>(cv);
        Proj3 pqk = {{x0, x1, nullptr}, {Wqb, Wkb, nullptr}, {bq, bk, nullptr},
                     {qp, kp, nullptr}, 0};
        gemm_proj<__bf16, __bf16><<<dim3(512 * 2), blk, 0, stream>>>(pqk);
        Cvt6 cvv = {{{values, x0, ABLK}, {nullptr, nullptr, 0}, {nullptr, nullptr, 0},
                     {nullptr, nullptr, 0}, {nullptr, nullptr, 0}, {nullptr, nullptr, 0}}};
        cvt_bf16<<<dim3(ABLK, 1), blk, 0, stream>>>(cvv);
        Proj3 pv = {{x0, nullptr, nullptr}, {Wvb, nullptr, nullptr},
                    {bv, nullptr, nullptr}, {vT, nullptr, nullptr}, 1};
        gemm_proj<__bf16, __bf16><<<dim3(512), blk, 0, stream>>>(pv);

        gemm_bt<true, false, true, float><<<dim3(544), blk, 0, stream>>>(
            kp, (long)SEQ * HD, HD, qp, (long)SEQ * HD, HD,
            outAttn, (long)SEQ * SEQ, SEQ, colsum, HD, 0.03125f);
        scale_emit<float><<<dim3(SEQ / 128, SEQ / 128, NB), blk, 0, stream>>>(
            outAttn, outAttn, colsum, attnT);
        gemm_bt<false, true, false, float><<<dim3(512), blk, 0, stream>>>(
            attnT, (long)SEQ * SEQ, SEQ, vT, (long)HD * SEQ, SEQ,
            outCtx, (long)SEQ * HD, HD, nullptr, SEQ, 1.0f);
    } else {
        // fallback: f32-staged operands straight from inputs; [qp][kp][vT]
        float* colsum = outCtx;
        hipMemsetAsync(colsum, 0, (size_t)NB * SEQ * sizeof(float), stream);
        qp = (__bf16*)w;
        kp = (__bf16*)(w + SLOT);
        vT = (__bf16*)(w + 2 * SLOT);
        __bf16* attnT = (__bf16*)d_ws;
        Proj3 pj = {{queries, keys, values}, {Wq, Wk, Wv}, {bq, bk, bv},
                    {qp, kp, vT}, 4};
        gemm_proj<float, float><<<dim3(512 * 3), blk, 0, stream>>>(pj);

        gemm_bt<true, false, true, float><<<dim3(544), blk, 0, stream>>>(
            kp, (long)SEQ * HD, HD, qp, (long)SEQ * HD, HD,
            outAttn, (long)SEQ * SEQ, SEQ, colsum, HD, 0.03125f);
        scale_emit<float><<<dim3(SEQ / 128, SEQ / 128, NB), blk, 0, stream>>>(
            outAttn, outAttn, colsum, attnT);
        gemm_bt<false, true, false, float><<<dim3(512), blk, 0, stream>>>(
            attnT, (long)SEQ * SEQ, SEQ, vT, (long)HD * SEQ, SEQ,
            outCtx, (long)SEQ * HD, HD, nullptr, SEQ, 1.0f);
    }
}